// Round 13
// baseline (275.909 us; speedup 1.0000x reference)
//
#include <hip/hip_runtime.h>

#define N_NODES 100000
#define N_EDGES 1600000
#define F_IN 128
#define F_OUT 64
#define BN_EPS 1e-5f

#define NCHUNK 128         // edge chunks
#define CHUNK_E 12500      // edges per chunk

#define SCAN_NB 98         // ceil(100000/1024) scan blocks

// ---------------- workspace layout (4-byte elements) ----------------
// s32    : [0,        1600000)   edge sources, int32
// d32    : [1600000,  3200000)   edge dests | rank<<27
// partial: [3200000,  6400000)   byte per (chunk, node): deg-nibble|cnt-nibble,
//                                then u8 cnt-prefix
// buck   : [6400000,  9600000)   int2 {src, ew-bits} per edge
// dinv   : [9600000,  9700000)
// sums   : [9700000,  9700128)
// off    : [9800128,  9900128)   block-local exclusive prefix (add bsum[n>>10])
// bsum   : [9900128,  9900256)
// hb     : ALIASES partial (sequential path, ws small) OR fresh region at
//          [9900288, 13100288) when ws_size permits (parallel place||gemm).

typedef __attribute__((ext_vector_type(8))) short bf16x8;
typedef __attribute__((ext_vector_type(4))) float f32x4;

__device__ __forceinline__ unsigned short f2bf(float x) {
    unsigned u = __float_as_uint(x);
    u += 0x7fffu + ((u >> 16) & 1u);   // RTNE
    return (unsigned short)(u >> 16);
}
__device__ __forceinline__ float4 bf4(uint2 p) {
    return make_float4(__int_as_float((int)(p.x << 16)),
                       __int_as_float((int)(p.x & 0xffff0000u)),
                       __int_as_float((int)(p.y << 16)),
                       __int_as_float((int)(p.y & 0xffff0000u)));
}

// R16 single-pass convert+count (512 thr validated). partial byte layout:
// byte b*100000 + node. d32[e] = d | rank<<27 from the LDS atomic return.
__global__ __launch_bounds__(512) void count_kernel(const void* __restrict__ ei,
                                                    int* __restrict__ s32,
                                                    int* __restrict__ d32,
                                                    unsigned* __restrict__ partial32) {
    __shared__ unsigned bins[N_NODES / 4];   // 100 KB
    const long long* q = (const long long*)ei;
    long long probe = q[threadIdx.x & 63];
    bool badp = (probe < 0 || probe >= N_NODES);
    int is64 = (__ballot(badp) == 0ULL);   // block-uniform

    const int tid = threadIdx.x;
    const int b = blockIdx.x;
    for (int i = tid; i < N_NODES / 4; i += 512) bins[i] = 0u;
    __syncthreads();
    const int e0 = b * CHUNK_E;
    for (int i = tid; i < CHUNK_E / 4; i += 512) {
        int e = e0 + i * 4;
        int4 s, d;
        if (is64) {
            longlong2 a = *(const longlong2*)&q[e];
            longlong2 bb = *(const longlong2*)&q[e + 2];
            s = make_int4((int)a.x, (int)a.y, (int)bb.x, (int)bb.y);
            longlong2 c2 = *(const longlong2*)&q[N_EDGES + e];
            longlong2 e2 = *(const longlong2*)&q[N_EDGES + e + 2];
            d = make_int4((int)c2.x, (int)c2.y, (int)e2.x, (int)e2.y);
        } else {
            s = ((const int4*)ei)[e >> 2];
            d = ((const int4*)ei)[(N_EDGES >> 2) + (e >> 2)];
        }
        ((int4*)s32)[e >> 2] = s;
#define C1(sk, dk, kk) { \
        unsigned si = (unsigned)(sk); \
        if (si < N_NODES) atomicAdd(&bins[si >> 2], 1u << ((si & 3) * 8)); \
        unsigned dd = (unsigned)(dk); \
        if (si < N_NODES && dd < N_NODES) { \
            unsigned sh = (dd & 3) * 8 + 4; \
            unsigned old = atomicAdd(&bins[dd >> 2], 16u << ((dd & 3) * 8)); \
            d32[e + kk] = (dk) | (int)(((old >> sh) & 0xFu) << 27); } }
        C1(s.x, d.x, 0) C1(s.y, d.y, 1) C1(s.z, d.z, 2) C1(s.w, d.w, 3)
#undef C1
    }
    __syncthreads();
    unsigned* dst = partial32 + (unsigned)b * (N_NODES / 4);
    for (int i = tid; i < N_NODES / 4; i += 512) dst[i] = bins[i];
}

// Fused reduce + scan1 (validated R9). Emits dinv, chunk-prefix bytes,
// block-local exclusive off, bsum[g].
__global__ __launch_bounds__(256) void redscan_kernel(unsigned* __restrict__ partial32,
                                                      float* __restrict__ dinv,
                                                      unsigned* __restrict__ off,
                                                      unsigned* __restrict__ bsum,
                                                      float* __restrict__ sums) {
    __shared__ unsigned s[256];
    const int tid = threadIdx.x;
    if (blockIdx.x == 0 && tid < 128) sums[tid] = 0.f;
    const int n0 = blockIdx.x * 1024 + tid * 4;
    unsigned cntk[4] = {0, 0, 0, 0};
    unsigned degk[4] = {0, 0, 0, 0};
    if (n0 < N_NODES) {
        unsigned idx = (unsigned)n0 >> 2;
#pragma unroll 8
        for (int c = 0; c < NCHUNK; ++c) {
            unsigned v = partial32[idx];
            unsigned nv = 0;
#pragma unroll
            for (int k = 0; k < 4; ++k) {
                unsigned byte = (v >> (k * 8)) & 0xFFu;
                nv |= (cntk[k] & 0xFFu) << (k * 8);
                cntk[k] += byte >> 4;
                degk[k] += byte & 0xFu;
            }
            partial32[idx] = nv;
            idx += N_NODES / 4;
        }
#pragma unroll
        for (int k = 0; k < 4; ++k)
            dinv[n0 + k] = rsqrtf((float)(degk[k] + 1u));
    }
    unsigned tsum = cntk[0] + cntk[1] + cntk[2] + cntk[3];
    s[tid] = tsum;
    __syncthreads();
    for (int d = 1; d < 256; d <<= 1) {
        unsigned t = (tid >= d) ? s[tid - d] : 0u;
        __syncthreads();
        s[tid] += t;
        __syncthreads();
    }
    unsigned run = s[tid] - tsum;
    if (n0 < N_NODES) {
        uint4 o;
        o.x = run;
        o.y = run + cntk[0];
        o.z = o.y + cntk[1];
        o.w = o.z + cntk[2];
        *(uint4*)&off[n0] = o;
    }
    if (tid == 255) bsum[blockIdx.x] = s[255];
}

__global__ __launch_bounds__(128) void scan2_kernel(unsigned* __restrict__ bsum) {
    __shared__ unsigned s[128];
    const int tid = threadIdx.x;
    unsigned v = (tid < SCAN_NB) ? bsum[tid] : 0u;
    s[tid] = v;
    __syncthreads();
    for (int d = 1; d < 128; d <<= 1) {
        unsigned t = (tid >= d) ? s[tid - d] : 0u;
        __syncthreads();
        s[tid] += t;
        __syncthreads();
    }
    if (tid < SCAN_NB) bsum[tid] = s[tid] - v;
}

// ---- place body (shared by sequential and fused kernels) ----
__device__ __forceinline__ void place_body(int i,
                                           const int* __restrict__ s32,
                                           const int* __restrict__ d32,
                                           const float* __restrict__ ew,
                                           const unsigned* __restrict__ off,
                                           const unsigned* __restrict__ bsum,
                                           const unsigned* __restrict__ partial32,
                                           int2* __restrict__ buck) {
    if (i >= N_EDGES / 4) return;
    int4 s = ((const int4*)s32)[i];
    int4 d = ((const int4*)d32)[i];
    float4 w = ((const float4*)ew)[i];
    const unsigned char* pb = (const unsigned char*)partial32;
    int e = i * 4;
    int b = e / CHUNK_E;   // e..e+3 in same chunk (CHUNK_E % 4 == 0)
    unsigned base = (unsigned)b * N_NODES;
#define P1(sk, dvk, wk) { \
    unsigned dd = (unsigned)(dvk) & 0x07FFFFFFu; \
    unsigned rk = ((unsigned)(dvk)) >> 27; \
    if ((unsigned)(sk) < N_NODES && dd < N_NODES) { \
        unsigned pref = pb[base + dd]; \
        unsigned slot = off[dd] + bsum[dd >> 10] + pref + rk; \
        if (slot < N_EDGES) \
            buck[slot] = make_int2((sk), __float_as_int(wk)); } }
    P1(s.x, d.x, w.x) P1(s.y, d.y, w.y) P1(s.z, d.z, w.z) P1(s.w, d.w, w.w)
#undef P1
}

// ---- gemm body (shared) ----
__device__ __forceinline__ void gemm_body(int gb, int tid,
                                          const float* __restrict__ x,
                                          const float* __restrict__ W,
                                          const float* __restrict__ dinv,
                                          unsigned short* __restrict__ hb,
                                          short* wlds) {
    const int n0 = gb * 64;
    {
        int out = tid & 63;
        int kb = tid >> 6;
#pragma unroll
        for (int i = 0; i < 4; ++i) {
            int koct = kb + i * 4;
            const float* wp = &W[out * F_IN + koct * 8];
            float4 aa = *(const float4*)wp;
            float4 bb = *(const float4*)(wp + 4);
            bf16x8 f;
            f[0] = (short)f2bf(aa.x); f[1] = (short)f2bf(aa.y);
            f[2] = (short)f2bf(aa.z); f[3] = (short)f2bf(aa.w);
            f[4] = (short)f2bf(bb.x); f[5] = (short)f2bf(bb.y);
            f[6] = (short)f2bf(bb.z); f[7] = (short)f2bf(bb.w);
            ((bf16x8*)wlds)[koct * 64 + out] = f;
        }
    }
    __syncthreads();
    const int wv = tid >> 6;
    const int lane = tid & 63;
    const int m = lane & 15;
    const int quad = lane >> 4;
    const int row = n0 + wv * 16 + m;
    const bool rv = row < N_NODES;
    const float* xrow = &x[(long)row * F_IN + quad * 8];
    f32x4 acc0 = {0.f, 0.f, 0.f, 0.f};
    f32x4 acc1 = {0.f, 0.f, 0.f, 0.f};
    f32x4 acc2 = {0.f, 0.f, 0.f, 0.f};
    f32x4 acc3 = {0.f, 0.f, 0.f, 0.f};
#pragma unroll
    for (int kc = 0; kc < 4; ++kc) {
        bf16x8 a = {0, 0, 0, 0, 0, 0, 0, 0};
        if (rv) {
            float4 aa = *(const float4*)(xrow + kc * 32);
            float4 bb = *(const float4*)(xrow + kc * 32 + 4);
            a[0] = (short)f2bf(aa.x); a[1] = (short)f2bf(aa.y);
            a[2] = (short)f2bf(aa.z); a[3] = (short)f2bf(aa.w);
            a[4] = (short)f2bf(bb.x); a[5] = (short)f2bf(bb.y);
            a[6] = (short)f2bf(bb.z); a[7] = (short)f2bf(bb.w);
        }
        const bf16x8* wrow = &((const bf16x8*)wlds)[(kc * 4 + quad) * 64 + m];
        acc0 = __builtin_amdgcn_mfma_f32_16x16x32_bf16(a, wrow[0],  acc0, 0, 0, 0);
        acc1 = __builtin_amdgcn_mfma_f32_16x16x32_bf16(a, wrow[16], acc1, 0, 0, 0);
        acc2 = __builtin_amdgcn_mfma_f32_16x16x32_bf16(a, wrow[32], acc2, 0, 0, 0);
        acc3 = __builtin_amdgcn_mfma_f32_16x16x32_bf16(a, wrow[48], acc3, 0, 0, 0);
    }
#pragma unroll
    for (int r = 0; r < 4; ++r) {
        int node = n0 + wv * 16 + quad * 4 + r;
        if (node < N_NODES) {
            float dv = dinv[node];
            unsigned short* hr = &hb[(long)node * F_OUT + m];
            hr[0]  = f2bf(acc0[r] * dv);
            hr[16] = f2bf(acc1[r] * dv);
            hr[32] = f2bf(acc2[r] * dv);
            hr[48] = f2bf(acc3[r] * dv);
        }
    }
}

// Sequential-path kernels (ws too small for fresh hb: hb aliases partial,
// so gemm must run after place).
__global__ __launch_bounds__(256) void place_kernel(const int* __restrict__ s32,
                                                    const int* __restrict__ d32,
                                                    const float* __restrict__ ew,
                                                    const unsigned* __restrict__ off,
                                                    const unsigned* __restrict__ bsum,
                                                    const unsigned* __restrict__ partial32,
                                                    int2* __restrict__ buck) {
    place_body(blockIdx.x * 256 + threadIdx.x, s32, d32, ew, off, bsum, partial32, buck);
}

__global__ __launch_bounds__(256) void gemm_kernel(const float* __restrict__ x,
                                                   const float* __restrict__ W,
                                                   const float* __restrict__ dinv,
                                                   unsigned short* __restrict__ hb) {
    __shared__ short wlds[16 * 64 * 8];   // 16 KB
    gemm_body(blockIdx.x, threadIdx.x, x, W, dinv, hb, wlds);
}

// R20 parallel path: place and gemm are data-independent (gemm needs only
// dinv, x, W); they were serialized solely by the hb/partial alias. With a
// fresh hb region they run in ONE launch: even blocks gemm, odd blocks place
// (block-uniform branch). Overlaps MFMA/read-bound gemm with latency/scatter-
// bound place.
__global__ __launch_bounds__(256) void place_gemm_kernel(
    const int* __restrict__ s32, const int* __restrict__ d32,
    const float* __restrict__ ew, const unsigned* __restrict__ off,
    const unsigned* __restrict__ bsum, const unsigned* __restrict__ partial32,
    int2* __restrict__ buck, const float* __restrict__ x,
    const float* __restrict__ W, const float* __restrict__ dinv,
    unsigned short* __restrict__ hb) {
    __shared__ short wlds[16 * 64 * 8];   // 16 KB (unused by place blocks)
    if (blockIdx.x & 1) {
        place_body((blockIdx.x >> 1) * 256 + threadIdx.x,
                   s32, d32, ew, off, bsum, partial32, buck);
    } else {
        gemm_body(blockIdx.x >> 1, threadIdx.x, x, W, dinv, hb, wlds);
    }
}

// Wave-per-node-range aggregation — R13/R16 validated config (NPW=13, 2048
// blocks, 3-deep edge-stream pipeline, int2 buck).
#define AGG_BLOCKS 2048
#define NPW 13   // ceil(100000 / 8192 waves)

#define ACC4(A, P, W) { \
    A[0] += __int_as_float((int)((P).x << 16)) * (W); \
    A[1] += __int_as_float((int)((P).x & 0xffff0000u)) * (W); \
    A[2] += __int_as_float((int)((P).y << 16)) * (W); \
    A[3] += __int_as_float((int)((P).y & 0xffff0000u)) * (W); }

#define LOADB(B0_, B1_, QV) { \
    unsigned a0_ = (QV) + (unsigned)es; \
    unsigned a1_ = a0_ + 4u; \
    if (a0_ > (unsigned)(N_EDGES - 1)) a0_ = (unsigned)(N_EDGES - 1); \
    if (a1_ > (unsigned)(N_EDGES - 1)) a1_ = (unsigned)(N_EDGES - 1); \
    B0_ = buck[a0_]; B1_ = buck[a1_]; }

#define GISSUE(G0_, G1_, W0_, W1_, B0_, B1_) { \
    unsigned r0_ = (unsigned)(B0_).x; if (r0_ > (unsigned)(N_NODES - 1)) r0_ = 0u; \
    unsigned r1_ = (unsigned)(B1_).x; if (r1_ > (unsigned)(N_NODES - 1)) r1_ = 0u; \
    G0_ = ((const uint2*)(hb + ((long)r0_ << 6)))[cl]; \
    G1_ = ((const uint2*)(hb + ((long)r1_ << 6)))[cl]; \
    W0_ = __int_as_float((B0_).y); W1_ = __int_as_float((B1_).y); }

#define FIN() { \
    acc[0] += __shfl_xor(acc[0], 16); acc[1] += __shfl_xor(acc[1], 16); \
    acc[2] += __shfl_xor(acc[2], 16); acc[3] += __shfl_xor(acc[3], 16); \
    acc[0] += __shfl_xor(acc[0], 32); acc[1] += __shfl_xor(acc[1], 32); \
    acc[2] += __shfl_xor(acc[2], 32); acc[3] += __shfl_xor(acc[3], 32); \
    if (es == 0) { \
        float4 hv = bf4(hn); \
        float r0_ = fmaxf(dn * (acc[0] + hv.x), 0.f); \
        float r1_ = fmaxf(dn * (acc[1] + hv.y), 0.f); \
        float r2_ = fmaxf(dn * (acc[2] + hv.z), 0.f); \
        float r3_ = fmaxf(dn * (acc[3] + hv.w), 0.f); \
        int node_ = nbeg + ncur; \
        *(float4*)&out[(long)node_ * F_OUT + cl * 4] = make_float4(r0_, r1_, r2_, r3_); \
        s1[0] += r0_; s1[1] += r1_; s1[2] += r2_; s1[3] += r3_; \
        s2[0] += r0_ * r0_; s2[1] += r1_ * r1_; \
        s2[2] += r2_ * r2_; s2[3] += r3_ * r3_; \
    } \
    acc[0] = acc[1] = acc[2] = acc[3] = 0.f; \
    ++ncur; \
    if (ncur < nn) { \
        seg_lo = bnd; \
        bnd = __shfl(bl, ncur + 1); \
        dn = __shfl(dvl, ncur); \
        hn = ((const uint2*)(hb + ((long)(nbeg + ncur) << 6)))[cl]; \
    } else { seg_lo = 0xFFFFFFFFu; bnd = 0xFFFFFFFFu; } }

#define CONSUME(G0_, G1_, W0_, W1_, QV) { \
    const unsigned qc_ = (QV); \
    const unsigned p0_ = qc_ + (unsigned)es; \
    const unsigned p1_ = p0_ + 4u; \
    for (;;) { \
        float m0_ = (p0_ >= seg_lo && p0_ < bnd) ? (W0_) : 0.f; \
        float m1_ = (p1_ >= seg_lo && p1_ < bnd) ? (W1_) : 0.f; \
        ACC4(acc, G0_, m0_) ACC4(acc, G1_, m1_) \
        if (bnd > qc_ + 8u) break; \
        FIN() \
        if (seg_lo >= qc_ + 8u) break; \
    } }

__global__ __launch_bounds__(256) void aggregate_kernel(
    const unsigned short* __restrict__ hb, const float* __restrict__ dinv,
    const unsigned* __restrict__ off, const unsigned* __restrict__ bsum,
    const int2* __restrict__ buck, float* __restrict__ out,
    float* __restrict__ sums) {
    const int tid = threadIdx.x;
    const int wv = tid >> 6;
    const int lane = tid & 63;
    const int es = lane >> 4;   // 4 edge slots
    const int cl = lane & 15;   // 16 channel lanes (uint2 = 4 channels)
    float s1[4] = {0.f, 0.f, 0.f, 0.f};
    float s2[4] = {0.f, 0.f, 0.f, 0.f};
    float acc[4] = {0.f, 0.f, 0.f, 0.f};

    const int wid = blockIdx.x * 4 + wv;
    const int nbeg = wid * NPW;
    int nn = N_NODES - nbeg;
    if (nn > NPW) nn = NPW;
    if (nn < 0) nn = 0;

    // lane-parallel preload of boundaries (lanes 0..nn) and dinv (lanes 0..nn-1)
    unsigned bl = (unsigned)N_EDGES;
    float dvl = 0.f;
    if (nn > 0) {
        int n = nbeg + lane;
        if (lane <= nn)
            bl = (n < N_NODES) ? off[n] + bsum[(unsigned)n >> 10] : (unsigned)N_EDGES;
        if (lane < nn) dvl = dinv[n];
    }

    if (nn > 0) {
        const unsigned obeg = __shfl(bl, 0);
        const unsigned oend = __shfl(bl, nn);
        int ncur = 0;
        unsigned seg_lo = obeg;
        unsigned bnd = __shfl(bl, 1);
        float dn = __shfl(dvl, 0);
        uint2 hn = ((const uint2*)(hb + ((long)nbeg << 6)))[cl];

        const int NB = (int)((oend - obeg + 7u) >> 3);
        const int NB3 = ((NB + 2) / 3) * 3;

        int2 b00, b01, b10, b11, b20, b21;
        uint2 gA0, gA1, gB0, gB1, gC0, gC1;
        float wA0, wA1, wB0, wB1, wC0, wC1;

        if (NB3 > 0) {
            LOADB(b00, b01, obeg)
            LOADB(b10, b11, obeg + 8u)
            LOADB(b20, b21, obeg + 16u)
            GISSUE(gA0, gA1, wA0, wA1, b00, b01) LOADB(b00, b01, obeg + 24u)
            GISSUE(gB0, gB1, wB0, wB1, b10, b11) LOADB(b10, b11, obeg + 32u)
            GISSUE(gC0, gC1, wC0, wC1, b20, b21) LOADB(b20, b21, obeg + 40u)

            for (int k = 3; k < NB3; k += 3) {
                const unsigned q = obeg + ((unsigned)k << 3);
                CONSUME(gA0, gA1, wA0, wA1, q - 24u)
                GISSUE(gA0, gA1, wA0, wA1, b00, b01) LOADB(b00, b01, q + 24u)
                CONSUME(gB0, gB1, wB0, wB1, q - 16u)
                GISSUE(gB0, gB1, wB0, wB1, b10, b11) LOADB(b10, b11, q + 32u)
                CONSUME(gC0, gC1, wC0, wC1, q - 8u)
                GISSUE(gC0, gC1, wC0, wC1, b20, b21) LOADB(b20, b21, q + 40u)
            }
            {
                const unsigned qd = obeg + ((unsigned)NB3 << 3);
                CONSUME(gA0, gA1, wA0, wA1, qd - 24u)
                CONSUME(gB0, gB1, wB0, wB1, qd - 16u)
                CONSUME(gC0, gC1, wC0, wC1, qd - 8u)
            }
        }
        // finalize any remaining (zero-edge) nodes
        while (ncur < nn) { FIN() }
    }

    __shared__ float l1[256];
    __shared__ float l2[256];
    if (es == 0) {
#pragma unroll
        for (int k = 0; k < 4; ++k) {
            l1[wv * 64 + cl * 4 + k] = s1[k];
            l2[wv * 64 + cl * 4 + k] = s2[k];
        }
    }
    __syncthreads();
    if (tid < 64) {
        float b1 = l1[tid] + l1[64 + tid] + l1[128 + tid] + l1[192 + tid];
        float b2 = l2[tid] + l2[64 + tid] + l2[128 + tid] + l2[192 + tid];
        atomicAdd(&sums[tid], b1);
        atomicAdd(&sums[64 + tid], b2);
    }
}

// BN apply with inline finalize (validated R9).
__global__ __launch_bounds__(256) void apply_kernel(float* __restrict__ agg,
                                                    const float* __restrict__ sums,
                                                    const float* __restrict__ gamma,
                                                    const float* __restrict__ beta) {
    __shared__ float sc[64], bi[64];
    if (threadIdx.x < 64) {
        int c = threadIdx.x;
        const float inv_n = 1.0f / (float)N_NODES;
        float mean = sums[c] * inv_n;
        float var = sums[64 + c] * inv_n - mean * mean;
        float rs = rsqrtf(var + BN_EPS);
        float scale = rs * gamma[c];
        sc[c] = scale;
        bi[c] = beta[c] - mean * scale;
    }
    __syncthreads();
    int i = blockIdx.x * blockDim.x + threadIdx.x;
    if (i >= N_NODES * 16) return;
    int c4 = (i & 15) << 2;
    float4 v = ((float4*)agg)[i];
    v.x = v.x * sc[c4 + 0] + bi[c4 + 0];
    v.y = v.y * sc[c4 + 1] + bi[c4 + 1];
    v.z = v.z * sc[c4 + 2] + bi[c4 + 2];
    v.w = v.w * sc[c4 + 3] + bi[c4 + 3];
    ((float4*)agg)[i] = v;
}

extern "C" void kernel_launch(void* const* d_in, const int* in_sizes, int n_in,
                              void* d_out, int out_size, void* d_ws, size_t ws_size,
                              hipStream_t stream) {
    const float* x     = (const float*)d_in[0];
    const void*  ei    = d_in[1];
    const float* ew    = (const float*)d_in[2];
    const float* W     = (const float*)d_in[3];
    const float* gamma = (const float*)d_in[4];
    const float* beta  = (const float*)d_in[5];
    float* out = (float*)d_out;
    float* ws  = (float*)d_ws;

    int*            s32       = (int*)ws;
    int*            d32       = (int*)(ws + 1600000);
    unsigned*       partial32 = (unsigned*)(ws + 3200000);
    int2*           buck      = (int2*)(ws + 6400000);
    float*          dinv      = ws + 9600000;
    float*          sums      = ws + 9700000;
    unsigned*       off       = (unsigned*)(ws + 9800128);
    unsigned*       bsum      = (unsigned*)(ws + 9900128);

    // Parallel path needs hb in fresh space: 9,900,288 + 3,200,000 floats.
    const bool big_ws = ws_size >= (size_t)(9900288 + 3200000) * 4;
    unsigned short* hb = big_ws ? (unsigned short*)(ws + 9900288)
                                : (unsigned short*)(ws + 3200000);  // alias partial

    count_kernel<<<NCHUNK, 512, 0, stream>>>(ei, s32, d32, partial32);
    redscan_kernel<<<SCAN_NB, 256, 0, stream>>>(partial32, dinv, off, bsum, sums);
    scan2_kernel<<<1, 128, 0, stream>>>(bsum);
    if (big_ws) {
        // place || gemm fused: even blocks gemm (1563), odd blocks place (1563)
        place_gemm_kernel<<<3126, 256, 0, stream>>>(s32, d32, ew, off, bsum,
                                                    partial32, buck, x, W, dinv, hb);
    } else {
        place_kernel<<<(N_EDGES / 4 + 255) / 256, 256, 0, stream>>>(s32, d32, ew, off, bsum,
                                                                    partial32, buck);
        gemm_kernel<<<(N_NODES + 63) / 64, 256, 0, stream>>>(x, W, dinv, hb);  // overwrites partial
    }
    aggregate_kernel<<<AGG_BLOCKS, 256, 0, stream>>>(hb, dinv, off, bsum, buck, out, sums);
    apply_kernel<<<(N_NODES * 16 + 255) / 256, 256, 0, stream>>>(out, sums, gamma, beta);
}

// Round 14
// 273.715 us; speedup vs baseline: 1.0080x; 1.0080x over previous
//
#include <hip/hip_runtime.h>

#define N_NODES 100000
#define N_EDGES 1600000
#define F_IN 128
#define F_OUT 64
#define BN_EPS 1e-5f

#define NCHUNK 128         // edge chunks
#define CHUNK_E 12500      // edges per chunk

#define SCAN_NB 98         // ceil(100000/1024) scan blocks

// ---------------- workspace layout (4-byte elements) ----------------
// s32    : [0,        1600000)   edge sources, int32
// d32    : [1600000,  3200000)   edge dests | rank<<27
// partial: [3200000,  6400000)   byte per (chunk, node): deg-nibble|cnt-nibble,
//                                then u8 cnt-prefix; hb (bf16 h') aliases after place
// buck   : [6400000,  9600000)   int2 {src, ew-bits} per edge
// dinv   : [9600000,  9700000)
// sums   : [9700000,  9700128)
// off    : [9800128,  9900128)   block-local exclusive prefix (add bsum[n>>10])
// bsum   : [9900128,  9900256)

typedef __attribute__((ext_vector_type(8))) short bf16x8;
typedef __attribute__((ext_vector_type(4))) float f32x4;

__device__ __forceinline__ unsigned short f2bf(float x) {
    unsigned u = __float_as_uint(x);
    u += 0x7fffu + ((u >> 16) & 1u);   // RTNE
    return (unsigned short)(u >> 16);
}
__device__ __forceinline__ float4 bf4(uint2 p) {
    return make_float4(__int_as_float((int)(p.x << 16)),
                       __int_as_float((int)(p.x & 0xffff0000u)),
                       __int_as_float((int)(p.y << 16)),
                       __int_as_float((int)(p.y & 0xffff0000u)));
}

// R16 single-pass convert+count (512 thr validated). partial byte layout:
// byte b*100000 + node. d32[e] = d | rank<<27 from the LDS atomic return.
__global__ __launch_bounds__(512) void count_kernel(const void* __restrict__ ei,
                                                    int* __restrict__ s32,
                                                    int* __restrict__ d32,
                                                    unsigned* __restrict__ partial32) {
    __shared__ unsigned bins[N_NODES / 4];   // 100 KB
    const long long* q = (const long long*)ei;
    long long probe = q[threadIdx.x & 63];
    bool badp = (probe < 0 || probe >= N_NODES);
    int is64 = (__ballot(badp) == 0ULL);   // block-uniform

    const int tid = threadIdx.x;
    const int b = blockIdx.x;
    for (int i = tid; i < N_NODES / 4; i += 512) bins[i] = 0u;
    __syncthreads();
    const int e0 = b * CHUNK_E;
    for (int i = tid; i < CHUNK_E / 4; i += 512) {
        int e = e0 + i * 4;
        int4 s, d;
        if (is64) {
            longlong2 a = *(const longlong2*)&q[e];
            longlong2 bb = *(const longlong2*)&q[e + 2];
            s = make_int4((int)a.x, (int)a.y, (int)bb.x, (int)bb.y);
            longlong2 c2 = *(const longlong2*)&q[N_EDGES + e];
            longlong2 e2 = *(const longlong2*)&q[N_EDGES + e + 2];
            d = make_int4((int)c2.x, (int)c2.y, (int)e2.x, (int)e2.y);
        } else {
            s = ((const int4*)ei)[e >> 2];
            d = ((const int4*)ei)[(N_EDGES >> 2) + (e >> 2)];
        }
        ((int4*)s32)[e >> 2] = s;
#define C1(sk, dk, kk) { \
        unsigned si = (unsigned)(sk); \
        if (si < N_NODES) atomicAdd(&bins[si >> 2], 1u << ((si & 3) * 8)); \
        unsigned dd = (unsigned)(dk); \
        if (si < N_NODES && dd < N_NODES) { \
            unsigned sh = (dd & 3) * 8 + 4; \
            unsigned old = atomicAdd(&bins[dd >> 2], 16u << ((dd & 3) * 8)); \
            d32[e + kk] = (dk) | (int)(((old >> sh) & 0xFu) << 27); } }
        C1(s.x, d.x, 0) C1(s.y, d.y, 1) C1(s.z, d.z, 2) C1(s.w, d.w, 3)
#undef C1
    }
    __syncthreads();
    unsigned* dst = partial32 + (unsigned)b * (N_NODES / 4);
    for (int i = tid; i < N_NODES / 4; i += 512) dst[i] = bins[i];
}

// Fused reduce + scan1. R21: chunk loop restructured into 4 batches of 32
// PREFETCHED loads (32 outstanding/thread vs unroll-8) — redscan runs at
// ~1.5 waves/CU, so per-thread MLP is the only latency lever. Emitted
// bytes bit-identical (dinv, chunk-prefix bytes, off, bsum).
__global__ __launch_bounds__(256) void redscan_kernel(unsigned* __restrict__ partial32,
                                                      float* __restrict__ dinv,
                                                      unsigned* __restrict__ off,
                                                      unsigned* __restrict__ bsum,
                                                      float* __restrict__ sums) {
    __shared__ unsigned s[256];
    const int tid = threadIdx.x;
    if (blockIdx.x == 0 && tid < 128) sums[tid] = 0.f;
    const int n0 = blockIdx.x * 1024 + tid * 4;
    unsigned cntk[4] = {0, 0, 0, 0};
    unsigned degk[4] = {0, 0, 0, 0};
    if (n0 < N_NODES) {
        unsigned idx = (unsigned)n0 >> 2;
        for (int cb = 0; cb < NCHUNK; cb += 32) {
            unsigned vv[32];
#pragma unroll
            for (int j = 0; j < 32; ++j)
                vv[j] = partial32[idx + (unsigned)j * (N_NODES / 4)];
#pragma unroll
            for (int j = 0; j < 32; ++j) {
                unsigned v = vv[j];
                unsigned nv = 0;
#pragma unroll
                for (int k = 0; k < 4; ++k) {
                    unsigned byte = (v >> (k * 8)) & 0xFFu;
                    nv |= (cntk[k] & 0xFFu) << (k * 8);
                    cntk[k] += byte >> 4;
                    degk[k] += byte & 0xFu;
                }
                partial32[idx + (unsigned)j * (N_NODES / 4)] = nv;
            }
            idx += 32u * (N_NODES / 4);
        }
#pragma unroll
        for (int k = 0; k < 4; ++k)
            dinv[n0 + k] = rsqrtf((float)(degk[k] + 1u));
    }
    unsigned tsum = cntk[0] + cntk[1] + cntk[2] + cntk[3];
    s[tid] = tsum;
    __syncthreads();
    for (int d = 1; d < 256; d <<= 1) {
        unsigned t = (tid >= d) ? s[tid - d] : 0u;
        __syncthreads();
        s[tid] += t;
        __syncthreads();
    }
    unsigned run = s[tid] - tsum;
    if (n0 < N_NODES) {
        uint4 o;
        o.x = run;
        o.y = run + cntk[0];
        o.z = o.y + cntk[1];
        o.w = o.z + cntk[2];
        *(uint4*)&off[n0] = o;
    }
    if (tid == 255) bsum[blockIdx.x] = s[255];
}

__global__ __launch_bounds__(128) void scan2_kernel(unsigned* __restrict__ bsum) {
    __shared__ unsigned s[128];
    const int tid = threadIdx.x;
    unsigned v = (tid < SCAN_NB) ? bsum[tid] : 0u;
    s[tid] = v;
    __syncthreads();
    for (int d = 1; d < 128; d <<= 1) {
        unsigned t = (tid >= d) ? s[tid - d] : 0u;
        __syncthreads();
        s[tid] += t;
        __syncthreads();
    }
    if (tid < SCAN_NB) bsum[tid] = s[tid] - v;
}

// Single-pass placement: slot = off[d] + bsum[d>>10] + chunk-prefix + rank,
// rank from d32 bits 27-30. Payload = {src, raw edge weight} (validated R16).
__global__ __launch_bounds__(256) void place_kernel(const int* __restrict__ s32,
                                                    const int* __restrict__ d32,
                                                    const float* __restrict__ ew,
                                                    const unsigned* __restrict__ off,
                                                    const unsigned* __restrict__ bsum,
                                                    const unsigned* __restrict__ partial32,
                                                    int2* __restrict__ buck) {
    int i = blockIdx.x * 256 + threadIdx.x;   // int4 index over edges
    if (i >= N_EDGES / 4) return;
    int4 s = ((const int4*)s32)[i];
    int4 d = ((const int4*)d32)[i];
    float4 w = ((const float4*)ew)[i];
    const unsigned char* pb = (const unsigned char*)partial32;
    int e = i * 4;
    int b = e / CHUNK_E;   // e..e+3 in same chunk (CHUNK_E % 4 == 0)
    unsigned base = (unsigned)b * N_NODES;
#define P1(sk, dvk, wk) { \
    unsigned dd = (unsigned)(dvk) & 0x07FFFFFFu; \
    unsigned rk = ((unsigned)(dvk)) >> 27; \
    if ((unsigned)(sk) < N_NODES && dd < N_NODES) { \
        unsigned pref = pb[base + dd]; \
        unsigned slot = off[dd] + bsum[dd >> 10] + pref + rk; \
        if (slot < N_EDGES) \
            buck[slot] = make_int2((sk), __float_as_int(wk)); } }
    P1(s.x, d.x, w.x) P1(s.y, d.y, w.y) P1(s.z, d.z, w.z) P1(s.w, d.w, w.w)
#undef P1
}

// h' = (x @ W^T) * dinv[row], stored bf16 via MFMA 16x16x32 (validated R6/R9).
__global__ __launch_bounds__(256) void gemm_kernel(const float* __restrict__ x,
                                                   const float* __restrict__ W,
                                                   const float* __restrict__ dinv,
                                                   unsigned short* __restrict__ hb) {
    __shared__ short wlds[16 * 64 * 8];   // 16 KB
    const int tid = threadIdx.x;
    const int n0 = blockIdx.x * 64;
    {
        int out = tid & 63;
        int kb = tid >> 6;
#pragma unroll
        for (int i = 0; i < 4; ++i) {
            int koct = kb + i * 4;
            const float* wp = &W[out * F_IN + koct * 8];
            float4 aa = *(const float4*)wp;
            float4 bb = *(const float4*)(wp + 4);
            bf16x8 f;
            f[0] = (short)f2bf(aa.x); f[1] = (short)f2bf(aa.y);
            f[2] = (short)f2bf(aa.z); f[3] = (short)f2bf(aa.w);
            f[4] = (short)f2bf(bb.x); f[5] = (short)f2bf(bb.y);
            f[6] = (short)f2bf(bb.z); f[7] = (short)f2bf(bb.w);
            ((bf16x8*)wlds)[koct * 64 + out] = f;
        }
    }
    __syncthreads();
    const int wv = tid >> 6;
    const int lane = tid & 63;
    const int m = lane & 15;
    const int quad = lane >> 4;
    const int row = n0 + wv * 16 + m;
    const bool rv = row < N_NODES;
    const float* xrow = &x[(long)row * F_IN + quad * 8];
    f32x4 acc0 = {0.f, 0.f, 0.f, 0.f};
    f32x4 acc1 = {0.f, 0.f, 0.f, 0.f};
    f32x4 acc2 = {0.f, 0.f, 0.f, 0.f};
    f32x4 acc3 = {0.f, 0.f, 0.f, 0.f};
#pragma unroll
    for (int kc = 0; kc < 4; ++kc) {
        bf16x8 a = {0, 0, 0, 0, 0, 0, 0, 0};
        if (rv) {
            float4 aa = *(const float4*)(xrow + kc * 32);
            float4 bb = *(const float4*)(xrow + kc * 32 + 4);
            a[0] = (short)f2bf(aa.x); a[1] = (short)f2bf(aa.y);
            a[2] = (short)f2bf(aa.z); a[3] = (short)f2bf(aa.w);
            a[4] = (short)f2bf(bb.x); a[5] = (short)f2bf(bb.y);
            a[6] = (short)f2bf(bb.z); a[7] = (short)f2bf(bb.w);
        }
        const bf16x8* wrow = &((const bf16x8*)wlds)[(kc * 4 + quad) * 64 + m];
        acc0 = __builtin_amdgcn_mfma_f32_16x16x32_bf16(a, wrow[0],  acc0, 0, 0, 0);
        acc1 = __builtin_amdgcn_mfma_f32_16x16x32_bf16(a, wrow[16], acc1, 0, 0, 0);
        acc2 = __builtin_amdgcn_mfma_f32_16x16x32_bf16(a, wrow[32], acc2, 0, 0, 0);
        acc3 = __builtin_amdgcn_mfma_f32_16x16x32_bf16(a, wrow[48], acc3, 0, 0, 0);
    }
#pragma unroll
    for (int r = 0; r < 4; ++r) {
        int node = n0 + wv * 16 + quad * 4 + r;
        if (node < N_NODES) {
            float dv = dinv[node];
            unsigned short* hr = &hb[(long)node * F_OUT + m];
            hr[0]  = f2bf(acc0[r] * dv);
            hr[16] = f2bf(acc1[r] * dv);
            hr[32] = f2bf(acc2[r] * dv);
            hr[48] = f2bf(acc3[r] * dv);
        }
    }
}

// Wave-per-node-range aggregation — R13/R16 validated config (NPW=13, 2048
// blocks, 3-deep edge-stream pipeline, int2 buck).
#define AGG_BLOCKS 2048
#define NPW 13   // ceil(100000 / 8192 waves)

#define ACC4(A, P, W) { \
    A[0] += __int_as_float((int)((P).x << 16)) * (W); \
    A[1] += __int_as_float((int)((P).x & 0xffff0000u)) * (W); \
    A[2] += __int_as_float((int)((P).y << 16)) * (W); \
    A[3] += __int_as_float((int)((P).y & 0xffff0000u)) * (W); }

#define LOADB(B0_, B1_, QV) { \
    unsigned a0_ = (QV) + (unsigned)es; \
    unsigned a1_ = a0_ + 4u; \
    if (a0_ > (unsigned)(N_EDGES - 1)) a0_ = (unsigned)(N_EDGES - 1); \
    if (a1_ > (unsigned)(N_EDGES - 1)) a1_ = (unsigned)(N_EDGES - 1); \
    B0_ = buck[a0_]; B1_ = buck[a1_]; }

#define GISSUE(G0_, G1_, W0_, W1_, B0_, B1_) { \
    unsigned r0_ = (unsigned)(B0_).x; if (r0_ > (unsigned)(N_NODES - 1)) r0_ = 0u; \
    unsigned r1_ = (unsigned)(B1_).x; if (r1_ > (unsigned)(N_NODES - 1)) r1_ = 0u; \
    G0_ = ((const uint2*)(hb + ((long)r0_ << 6)))[cl]; \
    G1_ = ((const uint2*)(hb + ((long)r1_ << 6)))[cl]; \
    W0_ = __int_as_float((B0_).y); W1_ = __int_as_float((B1_).y); }

#define FIN() { \
    acc[0] += __shfl_xor(acc[0], 16); acc[1] += __shfl_xor(acc[1], 16); \
    acc[2] += __shfl_xor(acc[2], 16); acc[3] += __shfl_xor(acc[3], 16); \
    acc[0] += __shfl_xor(acc[0], 32); acc[1] += __shfl_xor(acc[1], 32); \
    acc[2] += __shfl_xor(acc[2], 32); acc[3] += __shfl_xor(acc[3], 32); \
    if (es == 0) { \
        float4 hv = bf4(hn); \
        float r0_ = fmaxf(dn * (acc[0] + hv.x), 0.f); \
        float r1_ = fmaxf(dn * (acc[1] + hv.y), 0.f); \
        float r2_ = fmaxf(dn * (acc[2] + hv.z), 0.f); \
        float r3_ = fmaxf(dn * (acc[3] + hv.w), 0.f); \
        int node_ = nbeg + ncur; \
        *(float4*)&out[(long)node_ * F_OUT + cl * 4] = make_float4(r0_, r1_, r2_, r3_); \
        s1[0] += r0_; s1[1] += r1_; s1[2] += r2_; s1[3] += r3_; \
        s2[0] += r0_ * r0_; s2[1] += r1_ * r1_; \
        s2[2] += r2_ * r2_; s2[3] += r3_ * r3_; \
    } \
    acc[0] = acc[1] = acc[2] = acc[3] = 0.f; \
    ++ncur; \
    if (ncur < nn) { \
        seg_lo = bnd; \
        bnd = __shfl(bl, ncur + 1); \
        dn = __shfl(dvl, ncur); \
        hn = ((const uint2*)(hb + ((long)(nbeg + ncur) << 6)))[cl]; \
    } else { seg_lo = 0xFFFFFFFFu; bnd = 0xFFFFFFFFu; } }

#define CONSUME(G0_, G1_, W0_, W1_, QV) { \
    const unsigned qc_ = (QV); \
    const unsigned p0_ = qc_ + (unsigned)es; \
    const unsigned p1_ = p0_ + 4u; \
    for (;;) { \
        float m0_ = (p0_ >= seg_lo && p0_ < bnd) ? (W0_) : 0.f; \
        float m1_ = (p1_ >= seg_lo && p1_ < bnd) ? (W1_) : 0.f; \
        ACC4(acc, G0_, m0_) ACC4(acc, G1_, m1_) \
        if (bnd > qc_ + 8u) break; \
        FIN() \
        if (seg_lo >= qc_ + 8u) break; \
    } }

__global__ __launch_bounds__(256) void aggregate_kernel(
    const unsigned short* __restrict__ hb, const float* __restrict__ dinv,
    const unsigned* __restrict__ off, const unsigned* __restrict__ bsum,
    const int2* __restrict__ buck, float* __restrict__ out,
    float* __restrict__ sums) {
    const int tid = threadIdx.x;
    const int wv = tid >> 6;
    const int lane = tid & 63;
    const int es = lane >> 4;   // 4 edge slots
    const int cl = lane & 15;   // 16 channel lanes (uint2 = 4 channels)
    float s1[4] = {0.f, 0.f, 0.f, 0.f};
    float s2[4] = {0.f, 0.f, 0.f, 0.f};
    float acc[4] = {0.f, 0.f, 0.f, 0.f};

    const int wid = blockIdx.x * 4 + wv;
    const int nbeg = wid * NPW;
    int nn = N_NODES - nbeg;
    if (nn > NPW) nn = NPW;
    if (nn < 0) nn = 0;

    // lane-parallel preload of boundaries (lanes 0..nn) and dinv (lanes 0..nn-1)
    unsigned bl = (unsigned)N_EDGES;
    float dvl = 0.f;
    if (nn > 0) {
        int n = nbeg + lane;
        if (lane <= nn)
            bl = (n < N_NODES) ? off[n] + bsum[(unsigned)n >> 10] : (unsigned)N_EDGES;
        if (lane < nn) dvl = dinv[n];
    }

    if (nn > 0) {
        const unsigned obeg = __shfl(bl, 0);
        const unsigned oend = __shfl(bl, nn);
        int ncur = 0;
        unsigned seg_lo = obeg;
        unsigned bnd = __shfl(bl, 1);
        float dn = __shfl(dvl, 0);
        uint2 hn = ((const uint2*)(hb + ((long)nbeg << 6)))[cl];

        const int NB = (int)((oend - obeg + 7u) >> 3);
        const int NB3 = ((NB + 2) / 3) * 3;

        int2 b00, b01, b10, b11, b20, b21;
        uint2 gA0, gA1, gB0, gB1, gC0, gC1;
        float wA0, wA1, wB0, wB1, wC0, wC1;

        if (NB3 > 0) {
            LOADB(b00, b01, obeg)
            LOADB(b10, b11, obeg + 8u)
            LOADB(b20, b21, obeg + 16u)
            GISSUE(gA0, gA1, wA0, wA1, b00, b01) LOADB(b00, b01, obeg + 24u)
            GISSUE(gB0, gB1, wB0, wB1, b10, b11) LOADB(b10, b11, obeg + 32u)
            GISSUE(gC0, gC1, wC0, wC1, b20, b21) LOADB(b20, b21, obeg + 40u)

            for (int k = 3; k < NB3; k += 3) {
                const unsigned q = obeg + ((unsigned)k << 3);
                CONSUME(gA0, gA1, wA0, wA1, q - 24u)
                GISSUE(gA0, gA1, wA0, wA1, b00, b01) LOADB(b00, b01, q + 24u)
                CONSUME(gB0, gB1, wB0, wB1, q - 16u)
                GISSUE(gB0, gB1, wB0, wB1, b10, b11) LOADB(b10, b11, q + 32u)
                CONSUME(gC0, gC1, wC0, wC1, q - 8u)
                GISSUE(gC0, gC1, wC0, wC1, b20, b21) LOADB(b20, b21, q + 40u)
            }
            {
                const unsigned qd = obeg + ((unsigned)NB3 << 3);
                CONSUME(gA0, gA1, wA0, wA1, qd - 24u)
                CONSUME(gB0, gB1, wB0, wB1, qd - 16u)
                CONSUME(gC0, gC1, wC0, wC1, qd - 8u)
            }
        }
        // finalize any remaining (zero-edge) nodes
        while (ncur < nn) { FIN() }
    }

    __shared__ float l1[256];
    __shared__ float l2[256];
    if (es == 0) {
#pragma unroll
        for (int k = 0; k < 4; ++k) {
            l1[wv * 64 + cl * 4 + k] = s1[k];
            l2[wv * 64 + cl * 4 + k] = s2[k];
        }
    }
    __syncthreads();
    if (tid < 64) {
        float b1 = l1[tid] + l1[64 + tid] + l1[128 + tid] + l1[192 + tid];
        float b2 = l2[tid] + l2[64 + tid] + l2[128 + tid] + l2[192 + tid];
        atomicAdd(&sums[tid], b1);
        atomicAdd(&sums[64 + tid], b2);
    }
}

// BN apply with inline finalize (validated R9).
__global__ __launch_bounds__(256) void apply_kernel(float* __restrict__ agg,
                                                    const float* __restrict__ sums,
                                                    const float* __restrict__ gamma,
                                                    const float* __restrict__ beta) {
    __shared__ float sc[64], bi[64];
    if (threadIdx.x < 64) {
        int c = threadIdx.x;
        const float inv_n = 1.0f / (float)N_NODES;
        float mean = sums[c] * inv_n;
        float var = sums[64 + c] * inv_n - mean * mean;
        float rs = rsqrtf(var + BN_EPS);
        float scale = rs * gamma[c];
        sc[c] = scale;
        bi[c] = beta[c] - mean * scale;
    }
    __syncthreads();
    int i = blockIdx.x * blockDim.x + threadIdx.x;
    if (i >= N_NODES * 16) return;
    int c4 = (i & 15) << 2;
    float4 v = ((float4*)agg)[i];
    v.x = v.x * sc[c4 + 0] + bi[c4 + 0];
    v.y = v.y * sc[c4 + 1] + bi[c4 + 1];
    v.z = v.z * sc[c4 + 2] + bi[c4 + 2];
    v.w = v.w * sc[c4 + 3] + bi[c4 + 3];
    ((float4*)agg)[i] = v;
}

extern "C" void kernel_launch(void* const* d_in, const int* in_sizes, int n_in,
                              void* d_out, int out_size, void* d_ws, size_t ws_size,
                              hipStream_t stream) {
    const float* x     = (const float*)d_in[0];
    const void*  ei    = d_in[1];
    const float* ew    = (const float*)d_in[2];
    const float* W     = (const float*)d_in[3];
    const float* gamma = (const float*)d_in[4];
    const float* beta  = (const float*)d_in[5];
    float* out = (float*)d_out;
    float* ws  = (float*)d_ws;

    int*            s32       = (int*)ws;
    int*            d32       = (int*)(ws + 1600000);
    unsigned*       partial32 = (unsigned*)(ws + 3200000);
    unsigned short* hb        = (unsigned short*)(ws + 3200000);  // aliases partial
    int2*           buck      = (int2*)(ws + 6400000);
    float*          dinv      = ws + 9600000;
    float*          sums      = ws + 9700000;
    unsigned*       off       = (unsigned*)(ws + 9800128);
    unsigned*       bsum      = (unsigned*)(ws + 9900128);

    count_kernel<<<NCHUNK, 512, 0, stream>>>(ei, s32, d32, partial32);
    redscan_kernel<<<SCAN_NB, 256, 0, stream>>>(partial32, dinv, off, bsum, sums);
    scan2_kernel<<<1, 128, 0, stream>>>(bsum);
    place_kernel<<<(N_EDGES / 4 + 255) / 256, 256, 0, stream>>>(s32, d32, ew, off, bsum,
                                                                partial32, buck);
    gemm_kernel<<<(N_NODES + 63) / 64, 256, 0, stream>>>(x, W, dinv, hb);  // overwrites partial
    aggregate_kernel<<<AGG_BLOCKS, 256, 0, stream>>>(hb, dinv, off, bsum, buck, out, sums);
    apply_kernel<<<(N_NODES * 16 + 255) / 256, 256, 0, stream>>>(out, sums, gamma, beta);
}

// Round 15
// 257.874 us; speedup vs baseline: 1.0699x; 1.0614x over previous
//
#include <hip/hip_runtime.h>

#define N_NODES 100000
#define N_EDGES 1600000
#define F_IN 128
#define F_OUT 64
#define BN_EPS 1e-5f

#define NCHUNK 128         // edge chunks
#define CHUNK_E 12500      // edges per chunk

#define SCAN_NB 98         // ceil(100000/1024) scan blocks

// ---------------- workspace layout (4-byte elements) ----------------
// s32    : [0,        1600000)   edge sources, int32
// d32    : [1600000,  3200000)   edge dests | rank<<27
// partial: [3200000,  6400000)   byte per (chunk, node): deg-nibble|cnt-nibble,
//                                then u8 cnt-prefix; hb (bf16 h') aliases after place
// buck   : [6400000,  9600000)   int2 {src, ew-bits} per edge
// dinv   : [9600000,  9700000)
// sums   : [9700000,  9700128)
// off    : [9800128,  9900128)   block-local exclusive prefix (add bsum[n>>10])
// bsum   : [9900128,  9900256)

typedef __attribute__((ext_vector_type(8))) short bf16x8;
typedef __attribute__((ext_vector_type(4))) float f32x4;

__device__ __forceinline__ unsigned short f2bf(float x) {
    unsigned u = __float_as_uint(x);
    u += 0x7fffu + ((u >> 16) & 1u);   // RTNE
    return (unsigned short)(u >> 16);
}
__device__ __forceinline__ float4 bf4(uint2 p) {
    return make_float4(__int_as_float((int)(p.x << 16)),
                       __int_as_float((int)(p.x & 0xffff0000u)),
                       __int_as_float((int)(p.y << 16)),
                       __int_as_float((int)(p.y & 0xffff0000u)));
}

// R16 single-pass convert+count (512 thr validated). partial byte layout:
// byte b*100000 + node. d32[e] = d | rank<<27 from the LDS atomic return.
__global__ __launch_bounds__(512) void count_kernel(const void* __restrict__ ei,
                                                    int* __restrict__ s32,
                                                    int* __restrict__ d32,
                                                    unsigned* __restrict__ partial32) {
    __shared__ unsigned bins[N_NODES / 4];   // 100 KB
    const long long* q = (const long long*)ei;
    long long probe = q[threadIdx.x & 63];
    bool badp = (probe < 0 || probe >= N_NODES);
    int is64 = (__ballot(badp) == 0ULL);   // block-uniform

    const int tid = threadIdx.x;
    const int b = blockIdx.x;
    for (int i = tid; i < N_NODES / 4; i += 512) bins[i] = 0u;
    __syncthreads();
    const int e0 = b * CHUNK_E;
    for (int i = tid; i < CHUNK_E / 4; i += 512) {
        int e = e0 + i * 4;
        int4 s, d;
        if (is64) {
            longlong2 a = *(const longlong2*)&q[e];
            longlong2 bb = *(const longlong2*)&q[e + 2];
            s = make_int4((int)a.x, (int)a.y, (int)bb.x, (int)bb.y);
            longlong2 c2 = *(const longlong2*)&q[N_EDGES + e];
            longlong2 e2 = *(const longlong2*)&q[N_EDGES + e + 2];
            d = make_int4((int)c2.x, (int)c2.y, (int)e2.x, (int)e2.y);
        } else {
            s = ((const int4*)ei)[e >> 2];
            d = ((const int4*)ei)[(N_EDGES >> 2) + (e >> 2)];
        }
        ((int4*)s32)[e >> 2] = s;
#define C1(sk, dk, kk) { \
        unsigned si = (unsigned)(sk); \
        if (si < N_NODES) atomicAdd(&bins[si >> 2], 1u << ((si & 3) * 8)); \
        unsigned dd = (unsigned)(dk); \
        if (si < N_NODES && dd < N_NODES) { \
            unsigned sh = (dd & 3) * 8 + 4; \
            unsigned old = atomicAdd(&bins[dd >> 2], 16u << ((dd & 3) * 8)); \
            d32[e + kk] = (dk) | (int)(((old >> sh) & 0xFu) << 27); } }
        C1(s.x, d.x, 0) C1(s.y, d.y, 1) C1(s.z, d.z, 2) C1(s.w, d.w, 3)
#undef C1
    }
    __syncthreads();
    unsigned* dst = partial32 + (unsigned)b * (N_NODES / 4);
    for (int i = tid; i < N_NODES / 4; i += 512) dst[i] = bins[i];
}

// Fused reduce + scan1 (validated R9/R16). Emits dinv, chunk-prefix bytes,
// block-local exclusive off, bsum[g].
__global__ __launch_bounds__(256) void redscan_kernel(unsigned* __restrict__ partial32,
                                                      float* __restrict__ dinv,
                                                      unsigned* __restrict__ off,
                                                      unsigned* __restrict__ bsum,
                                                      float* __restrict__ sums) {
    __shared__ unsigned s[256];
    const int tid = threadIdx.x;
    if (blockIdx.x == 0 && tid < 128) sums[tid] = 0.f;
    const int n0 = blockIdx.x * 1024 + tid * 4;
    unsigned cntk[4] = {0, 0, 0, 0};
    unsigned degk[4] = {0, 0, 0, 0};
    if (n0 < N_NODES) {
        unsigned idx = (unsigned)n0 >> 2;
#pragma unroll 8
        for (int c = 0; c < NCHUNK; ++c) {
            unsigned v = partial32[idx];
            unsigned nv = 0;
#pragma unroll
            for (int k = 0; k < 4; ++k) {
                unsigned byte = (v >> (k * 8)) & 0xFFu;
                nv |= (cntk[k] & 0xFFu) << (k * 8);
                cntk[k] += byte >> 4;
                degk[k] += byte & 0xFu;
            }
            partial32[idx] = nv;
            idx += N_NODES / 4;
        }
#pragma unroll
        for (int k = 0; k < 4; ++k)
            dinv[n0 + k] = rsqrtf((float)(degk[k] + 1u));
    }
    unsigned tsum = cntk[0] + cntk[1] + cntk[2] + cntk[3];
    s[tid] = tsum;
    __syncthreads();
    for (int d = 1; d < 256; d <<= 1) {
        unsigned t = (tid >= d) ? s[tid - d] : 0u;
        __syncthreads();
        s[tid] += t;
        __syncthreads();
    }
    unsigned run = s[tid] - tsum;
    if (n0 < N_NODES) {
        uint4 o;
        o.x = run;
        o.y = run + cntk[0];
        o.z = o.y + cntk[1];
        o.w = o.z + cntk[2];
        *(uint4*)&off[n0] = o;
    }
    if (tid == 255) bsum[blockIdx.x] = s[255];
}

__global__ __launch_bounds__(128) void scan2_kernel(unsigned* __restrict__ bsum) {
    __shared__ unsigned s[128];
    const int tid = threadIdx.x;
    unsigned v = (tid < SCAN_NB) ? bsum[tid] : 0u;
    s[tid] = v;
    __syncthreads();
    for (int d = 1; d < 128; d <<= 1) {
        unsigned t = (tid >= d) ? s[tid - d] : 0u;
        __syncthreads();
        s[tid] += t;
        __syncthreads();
    }
    if (tid < SCAN_NB) bsum[tid] = s[tid] - v;
}

// Single-pass placement: slot = off[d] + bsum[d>>10] + chunk-prefix + rank,
// rank from d32 bits 27-30. Payload = {src, raw edge weight} (validated R16).
__global__ __launch_bounds__(256) void place_kernel(const int* __restrict__ s32,
                                                    const int* __restrict__ d32,
                                                    const float* __restrict__ ew,
                                                    const unsigned* __restrict__ off,
                                                    const unsigned* __restrict__ bsum,
                                                    const unsigned* __restrict__ partial32,
                                                    int2* __restrict__ buck) {
    int i = blockIdx.x * 256 + threadIdx.x;   // int4 index over edges
    if (i >= N_EDGES / 4) return;
    int4 s = ((const int4*)s32)[i];
    int4 d = ((const int4*)d32)[i];
    float4 w = ((const float4*)ew)[i];
    const unsigned char* pb = (const unsigned char*)partial32;
    int e = i * 4;
    int b = e / CHUNK_E;   // e..e+3 in same chunk (CHUNK_E % 4 == 0)
    unsigned base = (unsigned)b * N_NODES;
#define P1(sk, dvk, wk) { \
    unsigned dd = (unsigned)(dvk) & 0x07FFFFFFu; \
    unsigned rk = ((unsigned)(dvk)) >> 27; \
    if ((unsigned)(sk) < N_NODES && dd < N_NODES) { \
        unsigned pref = pb[base + dd]; \
        unsigned slot = off[dd] + bsum[dd >> 10] + pref + rk; \
        if (slot < N_EDGES) \
            buck[slot] = make_int2((sk), __float_as_int(wk)); } }
    P1(s.x, d.x, w.x) P1(s.y, d.y, w.y) P1(s.z, d.z, w.z) P1(s.w, d.w, w.w)
#undef P1
}

// h' = (x @ W^T) * dinv[row], stored bf16 via MFMA 16x16x32 (validated R6/R9).
__global__ __launch_bounds__(256) void gemm_kernel(const float* __restrict__ x,
                                                   const float* __restrict__ W,
                                                   const float* __restrict__ dinv,
                                                   unsigned short* __restrict__ hb) {
    __shared__ short wlds[16 * 64 * 8];   // 16 KB
    const int tid = threadIdx.x;
    const int n0 = blockIdx.x * 64;
    {
        int out = tid & 63;
        int kb = tid >> 6;
#pragma unroll
        for (int i = 0; i < 4; ++i) {
            int koct = kb + i * 4;
            const float* wp = &W[out * F_IN + koct * 8];
            float4 aa = *(const float4*)wp;
            float4 bb = *(const float4*)(wp + 4);
            bf16x8 f;
            f[0] = (short)f2bf(aa.x); f[1] = (short)f2bf(aa.y);
            f[2] = (short)f2bf(aa.z); f[3] = (short)f2bf(aa.w);
            f[4] = (short)f2bf(bb.x); f[5] = (short)f2bf(bb.y);
            f[6] = (short)f2bf(bb.z); f[7] = (short)f2bf(bb.w);
            ((bf16x8*)wlds)[koct * 64 + out] = f;
        }
    }
    __syncthreads();
    const int wv = tid >> 6;
    const int lane = tid & 63;
    const int m = lane & 15;
    const int quad = lane >> 4;
    const int row = n0 + wv * 16 + m;
    const bool rv = row < N_NODES;
    const float* xrow = &x[(long)row * F_IN + quad * 8];
    f32x4 acc0 = {0.f, 0.f, 0.f, 0.f};
    f32x4 acc1 = {0.f, 0.f, 0.f, 0.f};
    f32x4 acc2 = {0.f, 0.f, 0.f, 0.f};
    f32x4 acc3 = {0.f, 0.f, 0.f, 0.f};
#pragma unroll
    for (int kc = 0; kc < 4; ++kc) {
        bf16x8 a = {0, 0, 0, 0, 0, 0, 0, 0};
        if (rv) {
            float4 aa = *(const float4*)(xrow + kc * 32);
            float4 bb = *(const float4*)(xrow + kc * 32 + 4);
            a[0] = (short)f2bf(aa.x); a[1] = (short)f2bf(aa.y);
            a[2] = (short)f2bf(aa.z); a[3] = (short)f2bf(aa.w);
            a[4] = (short)f2bf(bb.x); a[5] = (short)f2bf(bb.y);
            a[6] = (short)f2bf(bb.z); a[7] = (short)f2bf(bb.w);
        }
        const bf16x8* wrow = &((const bf16x8*)wlds)[(kc * 4 + quad) * 64 + m];
        acc0 = __builtin_amdgcn_mfma_f32_16x16x32_bf16(a, wrow[0],  acc0, 0, 0, 0);
        acc1 = __builtin_amdgcn_mfma_f32_16x16x32_bf16(a, wrow[16], acc1, 0, 0, 0);
        acc2 = __builtin_amdgcn_mfma_f32_16x16x32_bf16(a, wrow[32], acc2, 0, 0, 0);
        acc3 = __builtin_amdgcn_mfma_f32_16x16x32_bf16(a, wrow[48], acc3, 0, 0, 0);
    }
#pragma unroll
    for (int r = 0; r < 4; ++r) {
        int node = n0 + wv * 16 + quad * 4 + r;
        if (node < N_NODES) {
            float dv = dinv[node];
            unsigned short* hr = &hb[(long)node * F_OUT + m];
            hr[0]  = f2bf(acc0[r] * dv);
            hr[16] = f2bf(acc1[r] * dv);
            hr[32] = f2bf(acc2[r] * dv);
            hr[48] = f2bf(acc3[r] * dv);
        }
    }
}

// Wave-per-node-range aggregation — R22: NPW response-curve probe.
// NPW=7@3572blk: 108 us (prologue/drain dominated); NPW=13@2048blk: 77.5 us.
// NPW=25@1024blk halves per-wave fixed cost again (4096 waves, 16 waves/CU
// potential vs measured ~10 resident).
#define AGG_BLOCKS 1024
#define NPW 25   // 1024 blocks * 4 waves * 25 >= 100000

#define ACC4(A, P, W) { \
    A[0] += __int_as_float((int)((P).x << 16)) * (W); \
    A[1] += __int_as_float((int)((P).x & 0xffff0000u)) * (W); \
    A[2] += __int_as_float((int)((P).y << 16)) * (W); \
    A[3] += __int_as_float((int)((P).y & 0xffff0000u)) * (W); }

#define LOADB(B0_, B1_, QV) { \
    unsigned a0_ = (QV) + (unsigned)es; \
    unsigned a1_ = a0_ + 4u; \
    if (a0_ > (unsigned)(N_EDGES - 1)) a0_ = (unsigned)(N_EDGES - 1); \
    if (a1_ > (unsigned)(N_EDGES - 1)) a1_ = (unsigned)(N_EDGES - 1); \
    B0_ = buck[a0_]; B1_ = buck[a1_]; }

#define GISSUE(G0_, G1_, W0_, W1_, B0_, B1_) { \
    unsigned r0_ = (unsigned)(B0_).x; if (r0_ > (unsigned)(N_NODES - 1)) r0_ = 0u; \
    unsigned r1_ = (unsigned)(B1_).x; if (r1_ > (unsigned)(N_NODES - 1)) r1_ = 0u; \
    G0_ = ((const uint2*)(hb + ((long)r0_ << 6)))[cl]; \
    G1_ = ((const uint2*)(hb + ((long)r1_ << 6)))[cl]; \
    W0_ = __int_as_float((B0_).y); W1_ = __int_as_float((B1_).y); }

#define FIN() { \
    acc[0] += __shfl_xor(acc[0], 16); acc[1] += __shfl_xor(acc[1], 16); \
    acc[2] += __shfl_xor(acc[2], 16); acc[3] += __shfl_xor(acc[3], 16); \
    acc[0] += __shfl_xor(acc[0], 32); acc[1] += __shfl_xor(acc[1], 32); \
    acc[2] += __shfl_xor(acc[2], 32); acc[3] += __shfl_xor(acc[3], 32); \
    if (es == 0) { \
        float4 hv = bf4(hn); \
        float r0_ = fmaxf(dn * (acc[0] + hv.x), 0.f); \
        float r1_ = fmaxf(dn * (acc[1] + hv.y), 0.f); \
        float r2_ = fmaxf(dn * (acc[2] + hv.z), 0.f); \
        float r3_ = fmaxf(dn * (acc[3] + hv.w), 0.f); \
        int node_ = nbeg + ncur; \
        *(float4*)&out[(long)node_ * F_OUT + cl * 4] = make_float4(r0_, r1_, r2_, r3_); \
        s1[0] += r0_; s1[1] += r1_; s1[2] += r2_; s1[3] += r3_; \
        s2[0] += r0_ * r0_; s2[1] += r1_ * r1_; \
        s2[2] += r2_ * r2_; s2[3] += r3_ * r3_; \
    } \
    acc[0] = acc[1] = acc[2] = acc[3] = 0.f; \
    ++ncur; \
    if (ncur < nn) { \
        seg_lo = bnd; \
        bnd = __shfl(bl, ncur + 1); \
        dn = __shfl(dvl, ncur); \
        hn = ((const uint2*)(hb + ((long)(nbeg + ncur) << 6)))[cl]; \
    } else { seg_lo = 0xFFFFFFFFu; bnd = 0xFFFFFFFFu; } }

#define CONSUME(G0_, G1_, W0_, W1_, QV) { \
    const unsigned qc_ = (QV); \
    const unsigned p0_ = qc_ + (unsigned)es; \
    const unsigned p1_ = p0_ + 4u; \
    for (;;) { \
        float m0_ = (p0_ >= seg_lo && p0_ < bnd) ? (W0_) : 0.f; \
        float m1_ = (p1_ >= seg_lo && p1_ < bnd) ? (W1_) : 0.f; \
        ACC4(acc, G0_, m0_) ACC4(acc, G1_, m1_) \
        if (bnd > qc_ + 8u) break; \
        FIN() \
        if (seg_lo >= qc_ + 8u) break; \
    } }

__global__ __launch_bounds__(256) void aggregate_kernel(
    const unsigned short* __restrict__ hb, const float* __restrict__ dinv,
    const unsigned* __restrict__ off, const unsigned* __restrict__ bsum,
    const int2* __restrict__ buck, float* __restrict__ out,
    float* __restrict__ sums) {
    const int tid = threadIdx.x;
    const int wv = tid >> 6;
    const int lane = tid & 63;
    const int es = lane >> 4;   // 4 edge slots
    const int cl = lane & 15;   // 16 channel lanes (uint2 = 4 channels)
    float s1[4] = {0.f, 0.f, 0.f, 0.f};
    float s2[4] = {0.f, 0.f, 0.f, 0.f};
    float acc[4] = {0.f, 0.f, 0.f, 0.f};

    const int wid = blockIdx.x * 4 + wv;
    const int nbeg = wid * NPW;
    int nn = N_NODES - nbeg;
    if (nn > NPW) nn = NPW;
    if (nn < 0) nn = 0;

    // lane-parallel preload of boundaries (lanes 0..nn) and dinv (lanes 0..nn-1)
    unsigned bl = (unsigned)N_EDGES;
    float dvl = 0.f;
    if (nn > 0) {
        int n = nbeg + lane;
        if (lane <= nn)
            bl = (n < N_NODES) ? off[n] + bsum[(unsigned)n >> 10] : (unsigned)N_EDGES;
        if (lane < nn) dvl = dinv[n];
    }

    if (nn > 0) {
        const unsigned obeg = __shfl(bl, 0);
        const unsigned oend = __shfl(bl, nn);
        int ncur = 0;
        unsigned seg_lo = obeg;
        unsigned bnd = __shfl(bl, 1);
        float dn = __shfl(dvl, 0);
        uint2 hn = ((const uint2*)(hb + ((long)nbeg << 6)))[cl];

        const int NB = (int)((oend - obeg + 7u) >> 3);
        const int NB3 = ((NB + 2) / 3) * 3;

        int2 b00, b01, b10, b11, b20, b21;
        uint2 gA0, gA1, gB0, gB1, gC0, gC1;
        float wA0, wA1, wB0, wB1, wC0, wC1;

        if (NB3 > 0) {
            LOADB(b00, b01, obeg)
            LOADB(b10, b11, obeg + 8u)
            LOADB(b20, b21, obeg + 16u)
            GISSUE(gA0, gA1, wA0, wA1, b00, b01) LOADB(b00, b01, obeg + 24u)
            GISSUE(gB0, gB1, wB0, wB1, b10, b11) LOADB(b10, b11, obeg + 32u)
            GISSUE(gC0, gC1, wC0, wC1, b20, b21) LOADB(b20, b21, obeg + 40u)

            for (int k = 3; k < NB3; k += 3) {
                const unsigned q = obeg + ((unsigned)k << 3);
                CONSUME(gA0, gA1, wA0, wA1, q - 24u)
                GISSUE(gA0, gA1, wA0, wA1, b00, b01) LOADB(b00, b01, q + 24u)
                CONSUME(gB0, gB1, wB0, wB1, q - 16u)
                GISSUE(gB0, gB1, wB0, wB1, b10, b11) LOADB(b10, b11, q + 32u)
                CONSUME(gC0, gC1, wC0, wC1, q - 8u)
                GISSUE(gC0, gC1, wC0, wC1, b20, b21) LOADB(b20, b21, q + 40u)
            }
            {
                const unsigned qd = obeg + ((unsigned)NB3 << 3);
                CONSUME(gA0, gA1, wA0, wA1, qd - 24u)
                CONSUME(gB0, gB1, wB0, wB1, qd - 16u)
                CONSUME(gC0, gC1, wC0, wC1, qd - 8u)
            }
        }
        // finalize any remaining (zero-edge) nodes
        while (ncur < nn) { FIN() }
    }

    __shared__ float l1[256];
    __shared__ float l2[256];
    if (es == 0) {
#pragma unroll
        for (int k = 0; k < 4; ++k) {
            l1[wv * 64 + cl * 4 + k] = s1[k];
            l2[wv * 64 + cl * 4 + k] = s2[k];
        }
    }
    __syncthreads();
    if (tid < 64) {
        float b1 = l1[tid] + l1[64 + tid] + l1[128 + tid] + l1[192 + tid];
        float b2 = l2[tid] + l2[64 + tid] + l2[128 + tid] + l2[192 + tid];
        atomicAdd(&sums[tid], b1);
        atomicAdd(&sums[64 + tid], b2);
    }
}

// BN apply with inline finalize (validated R9).
__global__ __launch_bounds__(256) void apply_kernel(float* __restrict__ agg,
                                                    const float* __restrict__ sums,
                                                    const float* __restrict__ gamma,
                                                    const float* __restrict__ beta) {
    __shared__ float sc[64], bi[64];
    if (threadIdx.x < 64) {
        int c = threadIdx.x;
        const float inv_n = 1.0f / (float)N_NODES;
        float mean = sums[c] * inv_n;
        float var = sums[64 + c] * inv_n - mean * mean;
        float rs = rsqrtf(var + BN_EPS);
        float scale = rs * gamma[c];
        sc[c] = scale;
        bi[c] = beta[c] - mean * scale;
    }
    __syncthreads();
    int i = blockIdx.x * blockDim.x + threadIdx.x;
    if (i >= N_NODES * 16) return;
    int c4 = (i & 15) << 2;
    float4 v = ((float4*)agg)[i];
    v.x = v.x * sc[c4 + 0] + bi[c4 + 0];
    v.y = v.y * sc[c4 + 1] + bi[c4 + 1];
    v.z = v.z * sc[c4 + 2] + bi[c4 + 2];
    v.w = v.w * sc[c4 + 3] + bi[c4 + 3];
    ((float4*)agg)[i] = v;
}

extern "C" void kernel_launch(void* const* d_in, const int* in_sizes, int n_in,
                              void* d_out, int out_size, void* d_ws, size_t ws_size,
                              hipStream_t stream) {
    const float* x     = (const float*)d_in[0];
    const void*  ei    = d_in[1];
    const float* ew    = (const float*)d_in[2];
    const float* W     = (const float*)d_in[3];
    const float* gamma = (const float*)d_in[4];
    const float* beta  = (const float*)d_in[5];
    float* out = (float*)d_out;
    float* ws  = (float*)d_ws;

    int*            s32       = (int*)ws;
    int*            d32       = (int*)(ws + 1600000);
    unsigned*       partial32 = (unsigned*)(ws + 3200000);
    unsigned short* hb        = (unsigned short*)(ws + 3200000);  // aliases partial
    int2*           buck      = (int2*)(ws + 6400000);
    float*          dinv      = ws + 9600000;
    float*          sums      = ws + 9700000;
    unsigned*       off       = (unsigned*)(ws + 9800128);
    unsigned*       bsum      = (unsigned*)(ws + 9900128);

    count_kernel<<<NCHUNK, 512, 0, stream>>>(ei, s32, d32, partial32);
    redscan_kernel<<<SCAN_NB, 256, 0, stream>>>(partial32, dinv, off, bsum, sums);
    scan2_kernel<<<1, 128, 0, stream>>>(bsum);
    place_kernel<<<(N_EDGES / 4 + 255) / 256, 256, 0, stream>>>(s32, d32, ew, off, bsum,
                                                                partial32, buck);
    gemm_kernel<<<(N_NODES + 63) / 64, 256, 0, stream>>>(x, W, dinv, hb);  // overwrites partial
    aggregate_kernel<<<AGG_BLOCKS, 256, 0, stream>>>(hb, dinv, off, bsum, buck, out, sums);
    apply_kernel<<<(N_NODES * 16 + 255) / 256, 256, 0, stream>>>(out, sums, gamma, beta);
}